// Round 11
// baseline (233.925 us; speedup 1.0000x reference)
//
#include <hip/hip_runtime.h>

#define NN 8000
#define NNP 8064              // padded j-stride for W / Ht (multiple of 64)
#define FD 256
#define NEG_SLOPE 0.2f

typedef __bf16 bf16;
typedef __bf16 bf16x8 __attribute__((ext_vector_type(8)));
typedef float f32x4 __attribute__((ext_vector_type(4)));

// ---------------- K1: H = X @ W^T + b -> Ht (bf16, [f][NNP]); zero out/lg/Ht-pad ----
__global__ __launch_bounds__(256) void k_linear(const float* __restrict__ X,
                                                const float* __restrict__ W,
                                                const float* __restrict__ b,
                                                bf16* __restrict__ Ht,
                                                float* __restrict__ out,
                                                float* __restrict__ lg) {
    __shared__ float Xs[16][260];
    const int t = threadIdx.x;
    const int i0 = blockIdx.x * 16;
    {   // zero out (8 MB), lg, and Ht's j-pad (256 rows x 64)
        const int gt = blockIdx.x * 256 + t;          // 128000 threads
        const float4 z4 = {0.f, 0.f, 0.f, 0.f};
        float4* o4 = (float4*)out;
        #pragma unroll
        for (int k = 0; k < 4; ++k) o4[gt + k * 128000] = z4;
        if (gt < NN) lg[gt] = 0.f;
        if (gt < FD * 8) {                            // 2048 x 16B = 256*64 bf16
            const int f = gt >> 3, p = gt & 7;
            *(int4*)&Ht[(size_t)f * NNP + NN + p * 8] = (int4){0, 0, 0, 0};
        }
    }
    #pragma unroll
    for (int r = 0; r < 16; ++r)
        Xs[r][t] = X[(size_t)(i0 + r) * FD + t];
    __syncthreads();
    const int f = t;
    float acc[16];
    const float bf_ = b[f];
    #pragma unroll
    for (int ii = 0; ii < 16; ++ii) acc[ii] = bf_;
    for (int k4 = 0; k4 < FD / 4; ++k4) {
        const float4 w4 = *(const float4*)&W[(size_t)f * FD + k4 * 4];
        #pragma unroll
        for (int ii = 0; ii < 16; ++ii) {
            const float4 x4 = *(const float4*)&Xs[ii][k4 * 4];
            acc[ii] += x4.x * w4.x + x4.y * w4.y + x4.z * w4.z + x4.w * w4.w;
        }
    }
    bf16x8 v0, v1;
    #pragma unroll
    for (int ii = 0; ii < 8; ++ii) { v0[ii] = (bf16)acc[ii]; v1[ii] = (bf16)acc[ii + 8]; }
    *(bf16x8*)&Ht[(size_t)f * NNP + i0]     = v0;
    *(bf16x8*)&Ht[(size_t)f * NNP + i0 + 8] = v1;
}

// ---------------- K2: hs = H@a_src + a_b, hd = H@a_dst ----------------
__global__ __launch_bounds__(256) void k_attn_vec(const bf16* __restrict__ Ht,
                                                  const float* __restrict__ a_src,
                                                  const float* __restrict__ a_dst,
                                                  const float* __restrict__ a_b,
                                                  float* __restrict__ hs,
                                                  float* __restrict__ hd) {
    __shared__ float psh[4][64], pdh[4][64];
    const int t = threadIdx.x;
    const int li = t & 63;
    const int q = t >> 6;
    const int i = blockIdx.x * 64 + li;
    float ps = 0.f, pd = 0.f;
    #pragma unroll 8
    for (int fi = 0; fi < 64; ++fi) {
        const int f = q * 64 + fi;
        const float h = (float)Ht[(size_t)f * NNP + i];
        ps += h * a_src[f];
        pd += h * a_dst[f];
    }
    psh[q][li] = ps; pdh[q][li] = pd;
    __syncthreads();
    if (q == 0) {
        ps = psh[0][li] + psh[1][li] + psh[2][li] + psh[3][li];
        pd = pdh[0][li] + pdh[1][li] + pdh[2][li] + pdh[3][li];
        hs[i] = ps + a_b[0];
        hd[i] = pd;
    }
}

__device__ __forceinline__ bf16x8 wgen8(int4 alo, int4 ahi, float4 hlo, float4 hhi,
                                        float hsv, float& ls) {
    float w[8]; float e;
    e = hsv + hlo.x; e = fmaxf(e, NEG_SLOPE * e); w[0] = alo.x ? __expf(e) : 0.f;
    e = hsv + hlo.y; e = fmaxf(e, NEG_SLOPE * e); w[1] = alo.y ? __expf(e) : 0.f;
    e = hsv + hlo.z; e = fmaxf(e, NEG_SLOPE * e); w[2] = alo.z ? __expf(e) : 0.f;
    e = hsv + hlo.w; e = fmaxf(e, NEG_SLOPE * e); w[3] = alo.w ? __expf(e) : 0.f;
    e = hsv + hhi.x; e = fmaxf(e, NEG_SLOPE * e); w[4] = ahi.x ? __expf(e) : 0.f;
    e = hsv + hhi.y; e = fmaxf(e, NEG_SLOPE * e); w[5] = ahi.y ? __expf(e) : 0.f;
    e = hsv + hhi.z; e = fmaxf(e, NEG_SLOPE * e); w[6] = ahi.z ? __expf(e) : 0.f;
    e = hsv + hhi.w; e = fmaxf(e, NEG_SLOPE * e); w[7] = ahi.w ? __expf(e) : 0.f;
    ls += ((w[0] + w[1]) + (w[2] + w[3])) + ((w[4] + w[5]) + (w[6] + w[7]));
    bf16x8 r;
    #pragma unroll
    for (int i = 0; i < 8; ++i) r[i] = (bf16)w[i];
    return r;
}

// ---------------- K3 (pass 1): stream adj -> W bf16 + row sums ----------------
// Pure streaming, grid-stride over tiles of 8 rows x 64 j per wave. No barriers,
// no MFMA. 32 waves/CU. Tail tile (jt==125) writes the j-pad zeros.
__global__ __launch_bounds__(256) void k_wgen(const int* __restrict__ adj,
                                              const float* __restrict__ hs,
                                              const float* __restrict__ hd,
                                              bf16* __restrict__ Wm,
                                              float* __restrict__ lg) {
    const int t = threadIdx.x;
    const int l = t & 63;
    const int wid = blockIdx.x * 4 + (t >> 6);
    const int nw = gridDim.x * 4;
    const int r = l >> 3, sl = l & 7;
    const int NT = 1000 * 126;                 // (8000/8 i-groups) x (8064/64 j-tiles)
    for (int tau = wid; tau < NT; tau += nw) {
        const int ig = tau / 126;
        const int jt = tau - ig * 126;
        const int i = ig * 8 + r;
        const int j0 = jt * 64 + sl * 8;
        bf16* wp = Wm + (size_t)i * NNP + j0;
        if (jt == 125) {                        // j-pad 8000..8063 -> zeros
            *(int4*)wp = (int4){0, 0, 0, 0};
            continue;
        }
        const int4 a0 = *(const int4*)(adj + (size_t)i * NN + j0);
        const int4 a1 = *(const int4*)(adj + (size_t)i * NN + j0 + 4);
        const float4 h0 = *(const float4*)(hd + j0);
        const float4 h1 = *(const float4*)(hd + j0 + 4);
        const float hsv = hs[i];
        float ls = 0.f;
        const bf16x8 w8 = wgen8(a0, a1, h0, h1, hsv, ls);
        *(bf16x8*)wp = w8;
        ls += __shfl_xor(ls, 1);
        ls += __shfl_xor(ls, 2);
        ls += __shfl_xor(ls, 4);
        if (sl == 0) atomicAdd(&lg[i], ls);
    }
}

// ---------------- K4 (pass 2): clean GEMM out = W x Ht^T ----------------
// 256 thr = 4 waves; block = 64 i x 256 f (wave fq owns 64 f); j-split x8
// (bid = jb*125 + ib so same-jb blocks are dispatch-adjacent -> Ht chunk L2-hot).
// W tile 64x64 staged via global_load_lds (source slot-XOR, linear LDS dest,
// read slot-XOR); Ht B-frags global->reg from L2. B loads issued BEFORE next
// stage so compiler's own wait is vmcnt(2) and the DMA stays in flight.
__global__ __launch_bounds__(256, 4) void k_pv(const bf16* __restrict__ Wm,
                                               const bf16* __restrict__ Ht,
                                               float* __restrict__ out) {
    __shared__ __attribute__((aligned(16))) bf16 As[2][64 * 64];   // 2 x 8 KB

    const int t  = threadIdx.x;
    const int l  = t & 63;
    const int fq = t >> 6;                // wave id = f quarter
    const int ib = blockIdx.x % 125;
    const int jb = blockIdx.x / 125;      // 0..7
    const int i0 = ib * 64;
    const int jq0 = jb * 1024;
    const int NS = (jb < 7) ? 16 : 14;    // 7*1024 + 896 = 8064 (pad j's have w=0)

    const int al = l & 15, asl = l >> 4;
    const int swz = al & 7;

    // stage W[i0..i0+64)[jq0+s*64 ..+64) -> As[buf]; linear dest, source slot-XOR
    auto stage = [&](int s_, int bufi) {
        #pragma unroll
        for (int q = 0; q < 2; ++q) {
            const int idx = q * 256 + t;
            const int row = idx >> 3;                    // 0..63
            const int slot = idx & 7;
            const bf16* src = Wm + (size_t)(i0 + row) * NNP + jq0 + s_ * 64
                              + ((slot ^ (row & 7)) * 8);
            bf16* dst = &As[bufi][idx * 8];
            __builtin_amdgcn_global_load_lds(
                (const __attribute__((address_space(1))) void*)src,
                (__attribute__((address_space(3))) void*)dst, 16, 0, 0);
        }
    };

    stage(0, 0);

    const bf16* htb = Ht + (size_t)(fq * 64 + al) * NNP + jq0 + asl * 8;

    f32x4 acc[4][4];
    #pragma unroll
    for (int rf = 0; rf < 4; ++rf)
        #pragma unroll
        for (int cf = 0; cf < 4; ++cf) acc[rf][cf] = (f32x4){0.f, 0.f, 0.f, 0.f};

    #pragma unroll 1
    for (int s = 0; s < NS; ++s) {
        const int cur = s & 1;

        // B-frags for this step FIRST (oldest) ...
        bf16x8 bfr[2][4];
        #pragma unroll
        for (int kk = 0; kk < 2; ++kk)
            #pragma unroll
            for (int cf = 0; cf < 4; ++cf)
                bfr[kk][cf] = *(const bf16x8*)(htb + (size_t)cf * 16 * NNP + s * 64 + kk * 32);
        __builtin_amdgcn_sched_barrier(0);
        // ... then next tile's DMA (newest)
        if (s + 1 < NS) stage(s + 1, cur ^ 1);

        // drain stage(s): 10 newer ops (8 B-loads + 2 DMA) may stay in flight
        if (s + 1 < NS) asm volatile("s_waitcnt vmcnt(10)" ::: "memory");
        else            asm volatile("s_waitcnt vmcnt(0)" ::: "memory");
        __builtin_amdgcn_s_barrier();

        const char* Ab = (const char*)&As[cur][0];
        #pragma unroll
        for (int kk = 0; kk < 2; ++kk) {
            #pragma unroll
            for (int rf = 0; rf < 4; ++rf) {
                const int row = rf * 16 + al;
                const bf16x8 a = *(const bf16x8*)(Ab + row * 128 +
                                                  (((kk * 4 + asl) ^ swz) << 4));
                acc[rf][0] = __builtin_amdgcn_mfma_f32_16x16x32_bf16(a, bfr[kk][0], acc[rf][0], 0, 0, 0);
                acc[rf][1] = __builtin_amdgcn_mfma_f32_16x16x32_bf16(a, bfr[kk][1], acc[rf][1], 0, 0, 0);
                acc[rf][2] = __builtin_amdgcn_mfma_f32_16x16x32_bf16(a, bfr[kk][2], acc[rf][2], 0, 0, 0);
                acc[rf][3] = __builtin_amdgcn_mfma_f32_16x16x32_bf16(a, bfr[kk][3], acc[rf][3], 0, 0, 0);
            }
        }
        asm volatile("s_waitcnt lgkmcnt(0)" ::: "memory");
        __builtin_amdgcn_s_barrier();   // reads of As[cur] done before s+2 restages it
    }

    // out[i][f]: D row = rf*16 + asl*4 + g (i), col = al (f); 8 contributions/elem
    #pragma unroll
    for (int rf = 0; rf < 4; ++rf) {
        #pragma unroll
        for (int cf = 0; cf < 4; ++cf) {
            #pragma unroll
            for (int g = 0; g < 4; ++g) {
                atomicAdd(&out[(size_t)(i0 + rf * 16 + asl * 4 + g) * FD
                               + fq * 64 + cf * 16 + al], acc[rf][cf][g]);
            }
        }
    }
}

// ---------------- K5: normalize by row sums ----------------
__global__ __launch_bounds__(256) void k_norm(float* __restrict__ out,
                                              const float* __restrict__ lg) {
    const int i = blockIdx.x;
    const float rinv = 1.0f / lg[i];
    out[(size_t)i * FD + threadIdx.x] *= rinv;
}

extern "C" void kernel_launch(void* const* d_in, const int* in_sizes, int n_in,
                              void* d_out, int out_size, void* d_ws, size_t ws_size,
                              hipStream_t stream) {
    const float* X     = (const float*)d_in[0];
    const int*   adj   = (const int*)d_in[1];
    const float* Ww    = (const float*)d_in[2];
    const float* Wb    = (const float*)d_in[3];
    const float* a_src = (const float*)d_in[4];
    const float* a_dst = (const float*)d_in[5];
    const float* a_b   = (const float*)d_in[6];
    float* out = (float*)d_out;

    bf16*  Ht = (bf16*)d_ws;                                  // 256*8064*2 = 4.13 MB
    float* hs = (float*)((char*)d_ws + (size_t)FD * NNP * sizeof(bf16));
    float* hd = hs + NN;
    float* lg = hd + NN;
    bf16*  Wm = (bf16*)(lg + NN);                             // 8000*8064*2 = 129 MB

    k_linear<<<NN / 16, 256, 0, stream>>>(X, Ww, Wb, Ht, out, lg);
    k_attn_vec<<<NN / 64, 256, 0, stream>>>(Ht, a_src, a_dst, a_b, hs, hd);
    k_wgen<<<2048, 256, 0, stream>>>(adj, hs, hd, Wm, lg);
    k_pv<<<125 * 8, 256, 0, stream>>>(Wm, Ht, out);
    k_norm<<<NN, 256, 0, stream>>>(out, lg);
}

// Round 12
// 159.902 us; speedup vs baseline: 1.4629x; 1.4629x over previous
//
#include <hip/hip_runtime.h>

#define NN 8000
#define FD 256
#define NEG_SLOPE 0.2f
#define BM 64
#define KT 64
#define BSTRIDE 128           // uint64 words per bits row (125 used, 1KB stride)

typedef __bf16 bf16;
typedef __bf16 bf16x8 __attribute__((ext_vector_type(8)));
typedef float f32x4 __attribute__((ext_vector_type(4)));
typedef unsigned long long u64;

// ---------------- K0: pack adj -> bitmask (8 MB) ----------------
// One wave per row. Lane l reads adj[i][w*64+l] (256B coalesced), ballot packs.
__global__ __launch_bounds__(256) void k_pack(const int* __restrict__ adj,
                                              u64* __restrict__ bits) {
    const int l = threadIdx.x & 63;
    const int i = blockIdx.x * 4 + (threadIdx.x >> 6);   // grid 2000 -> rows 0..7999
    const int* ap = adj + (size_t)i * NN + l;
    u64* bp = bits + (size_t)i * BSTRIDE;
    #pragma unroll 1
    for (int k8 = 0; k8 < 16; ++k8) {
        u64 myw = 0;
        #pragma unroll
        for (int sub = 0; sub < 8; ++sub) {
            const int w = k8 * 8 + sub;
            if (w < 125) {
                const int a = ap[(size_t)w * 64];
                const u64 m = __ballot(a != 0);
                if (l == sub) myw = m;
            }
        }
        if (l < 8 && (k8 * 8 + l) < 125) bp[k8 * 8 + l] = myw;
    }
}

// ---------------- K1: H = X @ W^T + b -> Ht (bf16, [f][i]); zero out/lg ----
__global__ __launch_bounds__(256) void k_linear(const float* __restrict__ X,
                                                const float* __restrict__ W,
                                                const float* __restrict__ b,
                                                bf16* __restrict__ Ht,
                                                float* __restrict__ out,
                                                float* __restrict__ lg) {
    __shared__ float Xs[16][260];
    const int t = threadIdx.x;
    const int i0 = blockIdx.x * 16;
    {   // zero out (8 MB) + lg
        const int gt = blockIdx.x * 256 + t;          // 128000 threads
        const float4 z4 = {0.f, 0.f, 0.f, 0.f};
        float4* o4 = (float4*)out;
        #pragma unroll
        for (int k = 0; k < 4; ++k) o4[gt + k * 128000] = z4;
        if (gt < NN) lg[gt] = 0.f;
    }
    #pragma unroll
    for (int r = 0; r < 16; ++r)
        Xs[r][t] = X[(size_t)(i0 + r) * FD + t];
    __syncthreads();
    const int f = t;
    float acc[16];
    const float bf_ = b[f];
    #pragma unroll
    for (int ii = 0; ii < 16; ++ii) acc[ii] = bf_;
    for (int k4 = 0; k4 < FD / 4; ++k4) {
        const float4 w4 = *(const float4*)&W[(size_t)f * FD + k4 * 4];
        #pragma unroll
        for (int ii = 0; ii < 16; ++ii) {
            const float4 x4 = *(const float4*)&Xs[ii][k4 * 4];
            acc[ii] += x4.x * w4.x + x4.y * w4.y + x4.z * w4.z + x4.w * w4.w;
        }
    }
    bf16x8 v0, v1;
    #pragma unroll
    for (int ii = 0; ii < 8; ++ii) { v0[ii] = (bf16)acc[ii]; v1[ii] = (bf16)acc[ii + 8]; }
    *(bf16x8*)&Ht[(size_t)f * NN + i0]     = v0;
    *(bf16x8*)&Ht[(size_t)f * NN + i0 + 8] = v1;
}

// ---------------- K2: hs = H@a_src + a_b, hd = H@a_dst ----------------
__global__ __launch_bounds__(256) void k_attn_vec(const bf16* __restrict__ Ht,
                                                  const float* __restrict__ a_src,
                                                  const float* __restrict__ a_dst,
                                                  const float* __restrict__ a_b,
                                                  float* __restrict__ hs,
                                                  float* __restrict__ hd) {
    __shared__ float psh[4][64], pdh[4][64];
    const int t = threadIdx.x;
    const int li = t & 63;
    const int q = t >> 6;
    const int i = blockIdx.x * 64 + li;
    float ps = 0.f, pd = 0.f;
    #pragma unroll 8
    for (int fi = 0; fi < 64; ++fi) {
        const int f = q * 64 + fi;
        const float h = (float)Ht[(size_t)f * NN + i];
        ps += h * a_src[f];
        pd += h * a_dst[f];
    }
    psh[q][li] = ps; pdh[q][li] = pd;
    __syncthreads();
    if (q == 0) {
        ps = psh[0][li] + psh[1][li] + psh[2][li] + psh[3][li];
        pd = pdh[0][li] + pdh[1][li] + pdh[2][li] + pdh[3][li];
        hs[i] = ps + a_b[0];
        hd[i] = pd;
    }
}

// ---------------- K3: fused GAT, all loop inputs L2-resident ----------------
// 512 thr (8 waves = 2 row-halves x 4 col-groups), BM=64, KT=64, j-split x4.
// Weight phase: thread owns row r=t>>3, 8 j's from ONE byte of the bits word
// (8B L2 load) + 2 float4 hd loads; 8 exps -> bf16x8 -> single ds_write_b128
// into single-buffered Wt. B tile (Ht 256f x 64j) via global_load_lds from
// L2-resident Ht, double-buffered, counted vmcnt(4). Two barriers/step.
__global__ __launch_bounds__(512, 4) void k_gat(const bf16* __restrict__ Ht,
                                                const u64* __restrict__ bits,
                                                const float* __restrict__ hs,
                                                const float* __restrict__ hd,
                                                float* __restrict__ out,
                                                float* __restrict__ lg) {
    __shared__ __attribute__((aligned(16))) bf16 Bt[2][FD * KT];  // 2 x 32 KB
    __shared__ __attribute__((aligned(16))) bf16 Wt[BM * KT];     // 8 KB (single)

    const int t  = threadIdx.x;
    const int l  = t & 63;
    const int wv = t >> 6;
    const int ib = blockIdx.x >> 2;
    const int jb = blockIdx.x & 3;
    const int i0 = ib * BM;
    const int jq0 = jb * 2048;
    const int NS = (jb < 3) ? 32 : 29;     // 3*2048 + 1856 = 8000

    // weight mapping: row r, byte b8 -> j = jq0 + s*64 + b8*8 + e
    const int r  = t >> 3;
    const int b8 = t & 7;
    const int jm = b8 * 8;
    const float hsv = hs[i0 + r];
    const u64* brow = bits + (size_t)(i0 + r) * BSTRIDE + (jq0 >> 6);
    const float* hdp = hd + jq0 + jm;
    const int woff = r * KT + ((b8 ^ (r & 7)) << 3);   // elems

    // MFMA mapping
    const int rh = wv >> 2, cg = wv & 3;
    const int al = l & 15, asl = l >> 4;

    auto stage = [&](int s_, int bufi) {
        #pragma unroll
        for (int q = 0; q < 4; ++q) {
            const int idx = q * 512 + t;
            const int col = idx >> 3;                 // f 0..255
            const int slot = idx & 7;
            const bf16* src = Ht + (size_t)col * NN + jq0 + s_ * KT
                              + ((slot ^ (col & 7)) * 8);
            bf16* dst = &Bt[bufi][idx * 8];
            __builtin_amdgcn_global_load_lds(
                (const __attribute__((address_space(1))) void*)src,
                (__attribute__((address_space(3))) void*)dst, 16, 0, 0);
        }
    };

    stage(0, 0);

    f32x4 acc[2][4];
    #pragma unroll
    for (int rb = 0; rb < 2; ++rb)
        #pragma unroll
        for (int cf = 0; cf < 4; ++cf) acc[rb][cf] = (f32x4){0.f, 0.f, 0.f, 0.f};
    float lsum = 0.f;

    #pragma unroll 1
    for (int s = 0; s < NS; ++s) {
        const int cur = s & 1;

        // weight-phase loads FIRST (older) ...
        const u64 word = brow[s];
        const float4 h0 = *(const float4*)(hdp + s * 64);
        const float4 h1 = *(const float4*)(hdp + s * 64 + 4);
        __builtin_amdgcn_sched_barrier(0);
        // ... then next tile's DMA (newer): wgen's implicit wait = vmcnt(4)
        if (s + 1 < NS) stage(s + 1, cur ^ 1);

        // weight phase: 8 w's from one byte
        {
            const unsigned int byte = (unsigned int)((word >> jm) & 0xffULL);
            float w[8]; float e;
            e = hsv + h0.x; e = fmaxf(e, NEG_SLOPE * e); w[0] = (byte & 1)   ? __expf(e) : 0.f;
            e = hsv + h0.y; e = fmaxf(e, NEG_SLOPE * e); w[1] = (byte & 2)   ? __expf(e) : 0.f;
            e = hsv + h0.z; e = fmaxf(e, NEG_SLOPE * e); w[2] = (byte & 4)   ? __expf(e) : 0.f;
            e = hsv + h0.w; e = fmaxf(e, NEG_SLOPE * e); w[3] = (byte & 8)   ? __expf(e) : 0.f;
            e = hsv + h1.x; e = fmaxf(e, NEG_SLOPE * e); w[4] = (byte & 16)  ? __expf(e) : 0.f;
            e = hsv + h1.y; e = fmaxf(e, NEG_SLOPE * e); w[5] = (byte & 32)  ? __expf(e) : 0.f;
            e = hsv + h1.z; e = fmaxf(e, NEG_SLOPE * e); w[6] = (byte & 64)  ? __expf(e) : 0.f;
            e = hsv + h1.w; e = fmaxf(e, NEG_SLOPE * e); w[7] = (byte & 128) ? __expf(e) : 0.f;
            lsum += ((w[0] + w[1]) + (w[2] + w[3])) + ((w[4] + w[5]) + (w[6] + w[7]));
            bf16x8 w8;
            #pragma unroll
            for (int e2 = 0; e2 < 8; ++e2) w8[e2] = (bf16)w[e2];
            *(bf16x8*)&Wt[woff] = w8;
        }

        // Bt[cur] complete (only stage(s+1)'s 4 DMA may remain in flight)
        if (s + 1 < NS) asm volatile("s_waitcnt vmcnt(4)" ::: "memory");
        else            asm volatile("s_waitcnt vmcnt(0)" ::: "memory");
        asm volatile("s_waitcnt lgkmcnt(0)" ::: "memory");
        __builtin_amdgcn_s_barrier();

        // MFMA: 2 row-frags x 4 col-frags x 2 k-halves = 16 MFMA
        {
            const char* Ab = (const char*)Wt;
            const char* Bb = (const char*)&Bt[cur][0];
            bf16x8 a[2][2], bb[4][2];
            #pragma unroll
            for (int rb = 0; rb < 2; ++rb) {
                const int row = rh * 32 + rb * 16 + al;
                #pragma unroll
                for (int kh = 0; kh < 2; ++kh)
                    a[rb][kh] = *(const bf16x8*)(Ab + row * 128 +
                                                 (((kh * 4 + asl) ^ (row & 7)) << 4));
            }
            #pragma unroll
            for (int cf = 0; cf < 4; ++cf) {
                const int col = cg * 64 + cf * 16 + al;
                #pragma unroll
                for (int kh = 0; kh < 2; ++kh)
                    bb[cf][kh] = *(const bf16x8*)(Bb + col * 128 +
                                                  (((kh * 4 + asl) ^ (col & 7)) << 4));
            }
            #pragma unroll
            for (int rb = 0; rb < 2; ++rb)
                #pragma unroll
                for (int cf = 0; cf < 4; ++cf) {
                    acc[rb][cf] = __builtin_amdgcn_mfma_f32_16x16x32_bf16(a[rb][0], bb[cf][0], acc[rb][cf], 0, 0, 0);
                    acc[rb][cf] = __builtin_amdgcn_mfma_f32_16x16x32_bf16(a[rb][1], bb[cf][1], acc[rb][cf], 0, 0, 0);
                }
        }
        asm volatile("s_waitcnt lgkmcnt(0)" ::: "memory");
        __builtin_amdgcn_s_barrier();   // Wt reads + Bt[cur] reads done
    }

    // row sums: 8 threads (t&7) share row r
    lsum += __shfl_xor(lsum, 1);
    lsum += __shfl_xor(lsum, 2);
    lsum += __shfl_xor(lsum, 4);
    if ((t & 7) == 0) atomicAdd(&lg[i0 + r], lsum);

    // numerator: 4 contributions per element
    #pragma unroll
    for (int rb = 0; rb < 2; ++rb)
        #pragma unroll
        for (int cf = 0; cf < 4; ++cf)
            #pragma unroll
            for (int g = 0; g < 4; ++g)
                atomicAdd(&out[(size_t)(i0 + rh * 32 + rb * 16 + asl * 4 + g) * FD
                               + cg * 64 + cf * 16 + al], acc[rb][cf][g]);
}

// ---------------- K4: normalize by row sums ----------------
__global__ __launch_bounds__(256) void k_norm(float* __restrict__ out,
                                              const float* __restrict__ lg) {
    const int i = blockIdx.x;
    const float rinv = 1.0f / lg[i];
    out[(size_t)i * FD + threadIdx.x] *= rinv;
}

extern "C" void kernel_launch(void* const* d_in, const int* in_sizes, int n_in,
                              void* d_out, int out_size, void* d_ws, size_t ws_size,
                              hipStream_t stream) {
    const float* X     = (const float*)d_in[0];
    const int*   adj   = (const int*)d_in[1];
    const float* Ww    = (const float*)d_in[2];
    const float* Wb    = (const float*)d_in[3];
    const float* a_src = (const float*)d_in[4];
    const float* a_dst = (const float*)d_in[5];
    const float* a_b   = (const float*)d_in[6];
    float* out = (float*)d_out;

    bf16*  Ht   = (bf16*)d_ws;                                // 4.096 MB
    float* hs   = (float*)((char*)d_ws + (size_t)FD * NN * sizeof(bf16));
    float* hd   = hs + NN;
    float* lg   = hd + NN;
    u64*   bits = (u64*)(lg + NN + 8);                        // 8.192 MB

    k_pack<<<NN / 4, 256, 0, stream>>>(adj, bits);
    k_linear<<<NN / 16, 256, 0, stream>>>(X, Ww, Wb, Ht, out, lg);
    k_attn_vec<<<NN / 64, 256, 0, stream>>>(Ht, a_src, a_dst, a_b, hs, hd);
    k_gat<<<(NN / BM) * 4, 512, 0, stream>>>(Ht, bits, hs, hd, out, lg);
    k_norm<<<NN, 256, 0, stream>>>(out, lg);
}